// Round 1
// baseline (94.998 us; speedup 1.0000x reference)
//
#include <hip/hip_runtime.h>

// Batched Thomas tridiagonal solve, B=8192 rows, N=4096.
// Row i coefficients (from alpha):
//   a_i = alpha[i-1]^2            (i>0; a_0 = 0)
//   b_i = max(5 + alpha[i]^3, 0.01)
//   c_i = alpha[i+1]^2 + 2*alpha[i+1]   (i<N-1; c_{N-1} unused since carry=0)
//   rhs f_i  (shared across rows)
//
// Strategy: chunked UL elimination with halos. System is strictly diagonally
// dominant (b>=5, |a|<=1, |c|<3) so influence decays >= 0.233/step forward,
// >= 0.70/step backward. Right halo H=32 (err ~1e-5 worst case), left halo
// HL=8 (err ~9e-6 worst case) vs threshold 2.25e-2.
//
// Per thread: backward elimination u_i = gp_i - ep_i * u_{i-1}, carried from
// i = e+H-1 down to i = s-HL, storing (gp,ep) for 72 elements in fully
// unrolled register arrays; then forward substitution writes 64 outputs
// (float4-packed). No global intermediates.

namespace {
constexpr int kB  = 8192;
constexpr int kN  = 4096;
constexpr int kM  = 64;         // outputs per thread
constexpr int kHL = 8;          // left (substitution) halo
constexpr int kH  = 32;         // right (elimination) halo
constexpr int kR  = kM + kHL;   // stored region = 72
constexpr int kNC = kN / kM;    // 64 chunks per row
constexpr int kBlocksPerChunk = kB / 256;  // 32
}

__global__ __launch_bounds__(256) void thomas_chunked(
    const float* __restrict__ alpha,
    const float* __restrict__ f,
    float* __restrict__ u)
{
  // chunk id scalar (SGPR): 32 consecutive blocks share one chunk
  const int k = blockIdx.x >> 5;
  const int r = ((blockIdx.x & 31) << 8) + threadIdx.x;   // row id
  const float* __restrict__ A = alpha + (size_t)r * kN;
  float*       __restrict__ U = u     + (size_t)r * kN;

  const bool first = (k == 0);
  const bool last  = (k == kNC - 1);
  const int  s   = k * kM;
  const int  sL  = first ? 0 : (s - kHL);               // stored region start
  const int  jhi = last ? (kN - 1) : (sL + kR + kH - 1); // sweep start index

  float gp[kR], ep[kR];
  float ec = 0.0f, gc = 0.0f;      // carry: u_{i+1} = gc - ec * u_i

  // rolling alpha regs: a0 = alpha[i], ap1 = alpha[i+1]
  float a0  = A[jhi];
  float ap1 = last ? 0.0f : A[jhi + 1];   // unused at first step (carry=0)

  // Phase A: right-halo descend, i = jhi .. sL+kR (no stores)
  if (!last) {
    #pragma unroll
    for (int t = 0; t < kH; ++t) {
      const int   i   = jhi - t;
      const float am1 = A[i - 1];                 // i-1 >= sL+kR-1 >= 71 > 0
      const float fi  = f[i];                     // scalar broadcast load
      const float c   = ap1 * (ap1 + 2.0f);
      const float b   = fmaxf(5.0f + a0 * a0 * a0, 0.01f);
      const float den = b - c * ec;
      const float rd  = __builtin_amdgcn_rcpf(den);
      gc = (fi - c * gc) * rd;
      ec = (am1 * am1) * rd;
      ap1 = a0; a0 = am1;
    }
  }

  // Phase B: stored sweep, i = sL+kR-1 .. sL  (t = i - sL)
  #pragma unroll
  for (int t = kR - 1; t >= 0; --t) {
    const int   ii  = sL + t;
    const float am1 = (ii > 0) ? A[ii - 1] : 0.0f;  // a_0 = 0 forced
    const float fi  = f[ii];
    const float c   = ap1 * (ap1 + 2.0f);
    const float b   = fmaxf(5.0f + a0 * a0 * a0, 0.01f);
    const float den = b - c * ec;
    const float rd  = __builtin_amdgcn_rcpf(den);
    gc = (fi - c * gc) * rd;
    ec = (am1 * am1) * rd;
    gp[t] = gc;
    ep[t] = ec;
    ap1 = a0; a0 = am1;
  }

  // Substitution: u_i = gp - ep * u_{i-1}, ascending; write t in [tmin, tmin+kM)
  const int tmin = first ? 0 : kHL;   // scalar; both values are mult of 4
  float up = 0.0f;                    // u_{sL-1} ~ 0 (exact for k==0; decays for k>0)
  float4 pk;
  #pragma unroll
  for (int t = 0; t < kR; ++t) {
    const float uv = fmaf(-ep[t], up, gp[t]);
    up = uv;
    const int ph = t & 3;
    if      (ph == 0) pk.x = uv;
    else if (ph == 1) pk.y = uv;
    else if (ph == 2) pk.z = uv;
    else {
      pk.w = uv;
      if (t - 3 >= tmin && t < tmin + kM) {   // group fully in/out (4-aligned)
        *reinterpret_cast<float4*>(&U[sL + t - 3]) = pk;
      }
    }
  }
}

extern "C" void kernel_launch(void* const* d_in, const int* in_sizes, int n_in,
                              void* d_out, int out_size, void* d_ws, size_t ws_size,
                              hipStream_t stream) {
  const float* alpha = (const float*)d_in[0];
  const float* f     = (const float*)d_in[1];
  float*       u     = (float*)d_out;
  const dim3 grid(kNC * kBlocksPerChunk);   // 64 * 32 = 2048 blocks
  thomas_chunked<<<grid, 256, 0, stream>>>(alpha, f, u);
}

// Round 2
// 78.357 us; speedup vs baseline: 1.2124x; 1.2124x over previous
//
#include <hip/hip_runtime.h>

// Batched Thomas tridiagonal solve, B=8192 rows, N=4096.
//   a_i = alpha[i-1]^2 (a_0=0); b_i = max(5+alpha[i]^3, 0.01);
//   c_i = alpha[i+1]^2 + 2*alpha[i+1]; rhs f (shared across rows).
//
// Chunked UL elimination with halos (diagonally dominant: b>=5, |a|<=1, |c|<3;
// backward influence decays <=0.70/step -> right halo H=32 err ~1e-5; forward
// decays <=0.235/step -> left halo HL=8 err ~9e-6; threshold 2.25e-2).
//
// R2 change: R1 was request-rate bound (64 distinct cache lines per wave load,
// VALUBusy 14%, HBM 33%). Now each block stages a 32-row x 560-col alpha panel
// into LDS with coalesced float4 loads; compute reads LDS at odd stride 561
// (conflict-free column access). Math identical to R1.

namespace {
constexpr int kN   = 4096;
constexpr int kM   = 64;            // outputs per thread
constexpr int kHL  = 8;             // left (substitution) halo
constexpr int kH   = 32;            // right (elimination) halo
constexpr int kR   = kM + kHL;      // stored region = 72
constexpr int kNC  = kN / kM;       // 64 chunks per row
constexpr int ROWS = 32;            // rows per block
constexpr int CPB  = 8;             // chunks per block
constexpr int THREADS = ROWS * CPB; // 256
constexpr int F4PR = 140;           // staged float4 per row (560 floats: [base-12, base+548))
constexpr int STRIDE = F4PR * 4 + 1; // 561 (odd -> conflict-free per-column LDS reads)
constexpr int STAGE_ITERS = (ROWS * F4PR + THREADS - 1) / THREADS; // 18
}

__global__ __launch_bounds__(THREADS) void thomas_lds(
    const float* __restrict__ alpha,
    const float* __restrict__ f,
    float* __restrict__ u)
{
  __shared__ float sA[ROWS * STRIDE];   // 71808 B
  __shared__ float sF[F4PR * 4];        // 2240 B

  const int bid  = blockIdx.x;
  const int cg   = bid & 7;               // chunk group (8 per row)
  const int r0   = (bid >> 3) * ROWS;     // first row of block
  const int base = cg * (CPB * kM);       // cg*512
  const int cbase4 = cg * 128 - 3;        // first staged global f4 index (may be <0)
  const int tid  = threadIdx.x;

  // ---- stage alpha panel: coalesced float4 loads ----
  #pragma unroll
  for (int it = 0; it < STAGE_ITERS; ++it) {
    const int idx = tid + it * THREADS;
    if (idx < ROWS * F4PR) {
      const int row = idx / F4PR;
      const int c4  = idx - row * F4PR;
      int g4 = cbase4 + c4;
      g4 = (g4 < 0) ? 0 : ((g4 > kN / 4 - 1) ? kN / 4 - 1 : g4);  // clamp (dup values unused)
      const float4 v = *reinterpret_cast<const float4*>(
          alpha + (size_t)(r0 + row) * kN + (size_t)g4 * 4);
      float* dst = &sA[row * STRIDE + c4 * 4];
      dst[0] = v.x; dst[1] = v.y; dst[2] = v.z; dst[3] = v.w;
    }
  }
  // ---- stage f row ----
  if (tid < F4PR) {
    int g4 = cbase4 + tid;
    g4 = (g4 < 0) ? 0 : ((g4 > kN / 4 - 1) ? kN / 4 - 1 : g4);
    const float4 v = *reinterpret_cast<const float4*>(f + (size_t)g4 * 4);
    float* dst = &sF[tid * 4];
    dst[0] = v.x; dst[1] = v.y; dst[2] = v.z; dst[3] = v.w;
  }
  __syncthreads();

  // ---- per-thread chunk solve (reads from LDS) ----
  const int j = tid & 31;          // row-local: wave = 32 rows x 2 chunks
  const int q = tid >> 5;          // chunk-local 0..7
  const int k = cg * CPB + q;      // global chunk id
  const int r = r0 + j;
  const float* __restrict__ Arow = &sA[j * STRIDE];
  float* __restrict__ U = u + (size_t)r * kN;
  const int off = 12 - base;       // LDS index li = i + off for global col i

  const bool first = (k == 0);
  const bool last  = (k == kNC - 1);
  const int  s   = k * kM;
  const int  sL  = first ? 0 : (s - kHL);
  const int  jhi = last ? (kN - 1) : (sL + kR + kH - 1);

  float gp[kR], ep[kR];
  float ec = 0.0f, gc = 0.0f;          // carry: u_{i+1} = gc - ec * u_i

  float a0  = Arow[jhi + off];
  float ap1 = last ? 0.0f : Arow[jhi + 1 + off];

  // Phase A: right-halo descend (no stores)
  if (!last) {
    #pragma unroll
    for (int t = 0; t < kH; ++t) {
      const int   i   = jhi - t;
      const float am1 = Arow[i - 1 + off];
      const float fi  = sF[i + off];
      const float c   = ap1 * (ap1 + 2.0f);
      const float b   = fmaxf(5.0f + a0 * a0 * a0, 0.01f);
      const float den = b - c * ec;
      const float rd  = __builtin_amdgcn_rcpf(den);
      gc = (fi - c * gc) * rd;
      ec = (am1 * am1) * rd;
      ap1 = a0; a0 = am1;
    }
  }

  // Phase B: stored sweep, t = i - sL descending
  #pragma unroll
  for (int t = kR - 1; t >= 0; --t) {
    const int   ii  = sL + t;
    const float am1 = (ii > 0) ? Arow[ii - 1 + off] : 0.0f;
    const float fi  = sF[ii + off];
    const float c   = ap1 * (ap1 + 2.0f);
    const float b   = fmaxf(5.0f + a0 * a0 * a0, 0.01f);
    const float den = b - c * ec;
    const float rd  = __builtin_amdgcn_rcpf(den);
    gc = (fi - c * gc) * rd;
    ec = (am1 * am1) * rd;
    gp[t] = gc;
    ep[t] = ec;
    ap1 = a0; a0 = am1;
  }

  // Substitution: u_i = gp - ep * u_{i-1}, ascending; write t in [tmin, tmin+kM)
  const int tmin = first ? 0 : kHL;
  float up = 0.0f;
  float4 pk;
  #pragma unroll
  for (int t = 0; t < kR; ++t) {
    const float uv = fmaf(-ep[t], up, gp[t]);
    up = uv;
    const int ph = t & 3;
    if      (ph == 0) pk.x = uv;
    else if (ph == 1) pk.y = uv;
    else if (ph == 2) pk.z = uv;
    else {
      pk.w = uv;
      if (t - 3 >= tmin && t < tmin + kM) {
        *reinterpret_cast<float4*>(&U[sL + t - 3]) = pk;
      }
    }
  }
}

extern "C" void kernel_launch(void* const* d_in, const int* in_sizes, int n_in,
                              void* d_out, int out_size, void* d_ws, size_t ws_size,
                              hipStream_t stream) {
  const float* alpha = (const float*)d_in[0];
  const float* f     = (const float*)d_in[1];
  float*       uo    = (float*)d_out;
  const dim3 grid((8192 / ROWS) * (kNC / CPB));   // 256 * 8 = 2048 blocks
  thomas_lds<<<grid, THREADS, 0, stream>>>(alpha, f, uo);
}

// Round 3
// 77.329 us; speedup vs baseline: 1.2285x; 1.0133x over previous
//
#include <hip/hip_runtime.h>

// Batched Thomas tridiagonal solve, B=8192 rows, N=4096.
//   a_i = alpha[i-1]^2 (a_0=0); b_i = max(5+alpha[i]^3, 0.01);
//   c_i = alpha[i+1]^2 + 2*alpha[i+1]; rhs f (shared across rows).
//
// Chunked UL elimination with halos (diag dominant: backward decay <=0.70/step
// -> right halo H=32 err ~1e-5; forward decay <=0.235/step -> left halo HL=8).
//
// R3: chunk 32 (regs 144->80 floats, LDS 74->40.6KB -> 4 blocks/CU = 16
// waves/CU), ds_read_b128 alpha/f (stride 308 dw == 20 mod 32: all-bank
// coverage), explicit 2-group float4 prefetch pipeline. Math identical.

namespace {
constexpr int kN   = 4096;
constexpr int kCH  = 32;             // outputs per thread
constexpr int kHL  = 8;              // left halo
constexpr int kH   = 32;             // right halo
constexpr int kR   = kCH + kHL;      // stored region = 40 (10 groups of 4)
constexpr int kNC  = kN / kCH;       // 128 chunks per row
constexpr int ROWS = 32;
constexpr int CPB  = 8;              // chunks per block
constexpr int THREADS = ROWS * CPB;  // 256
constexpr int F4PR = 76;             // staged float4/row: cols [base-12, base+292)
constexpr int STRIDE_DW = 308;       // 76*4 + 4 pad; 308 % 32 == 20 (4*odd)
}

__global__ __launch_bounds__(THREADS) void thomas_v3(
    const float* __restrict__ alpha,
    const float* __restrict__ f,
    float* __restrict__ u)
{
  __shared__ float sA[ROWS * STRIDE_DW];   // 39424 B
  __shared__ float sF[F4PR * 4];           // 1216 B  (total 40640 -> 4 blocks/CU)

  const int bid  = blockIdx.x;
  const int cg   = bid & 15;               // chunk group (16 per row)
  const int r0   = (bid >> 4) * ROWS;
  const int base = cg * (CPB * kCH);       // cg*256
  const int cbase4 = cg * 64 - 3;          // first staged global f4 index
  const int tid  = threadIdx.x;

  // ---- stage alpha panel (coalesced float4) ----
  #pragma unroll
  for (int it = 0; it < 10; ++it) {
    const int idx = tid + it * THREADS;
    if (idx < ROWS * F4PR) {
      const int row = idx / F4PR;
      const int c4  = idx - row * F4PR;
      int g4 = cbase4 + c4;
      g4 = (g4 < 0) ? 0 : ((g4 > kN / 4 - 1) ? kN / 4 - 1 : g4);  // clamp; dups unused
      const float4 v = *reinterpret_cast<const float4*>(
          alpha + (size_t)(r0 + row) * kN + (size_t)g4 * 4);
      *reinterpret_cast<float4*>(&sA[row * STRIDE_DW + c4 * 4]) = v;
    }
  }
  if (tid < F4PR) {
    int g4 = cbase4 + tid;
    g4 = (g4 < 0) ? 0 : ((g4 > kN / 4 - 1) ? kN / 4 - 1 : g4);
    *reinterpret_cast<float4*>(&sF[tid * 4]) =
        *reinterpret_cast<const float4*>(f + (size_t)g4 * 4);
  }
  __syncthreads();

  // ---- per-thread chunk solve ----
  const int j = tid & 31;                  // row-local
  const int q = tid >> 5;                  // chunk-local 0..7
  const int k = cg * CPB + q;
  const int r = r0 + j;
  float* __restrict__ U = u + (size_t)r * kN;

  const bool first = (k == 0);
  const bool last  = (k == kNC - 1);
  const int  s   = k * kCH;
  const int  sL  = first ? 0 : (s - kHL);
  const int  off = 12 - base;              // LDS dword = global col + off
  const int  f4b = (sL + off) >> 2;        // LDS f4 index of group 0

  const float4* __restrict__ A4 = reinterpret_cast<const float4*>(&sA[j * STRIDE_DW]);
  const float4* __restrict__ F4 = reinterpret_cast<const float4*>(sF);

  float gp[kR], ep[kR];
  float ec = 0.0f, gc = 0.0f, ap1 = 0.0f;  // zero carry: first step's c*carry = 0,
                                           // so ap1 seed value is irrelevant.
  const int ghi = last ? 9 : 17;           // highest group (g in [0,ghi])
  float4 curA = A4[f4b + ghi];
  float4 lowA = A4[f4b + ghi - 1];
  float4 fcur = F4[f4b + ghi];
  float4 flow = F4[f4b + ghi - 1];
  float a0 = curA.w;                       // alpha[sL + 4*ghi + 3] = alpha[jhi]

#define STEP(am1v, fiv)                                        \
  {                                                            \
    const float c_  = ap1 * (ap1 + 2.0f);                      \
    const float b_  = fmaxf(fmaf(a0 * a0, a0, 5.0f), 0.01f);   \
    const float dn  = fmaf(-c_, ec, b_);                       \
    const float rd  = __builtin_amdgcn_rcpf(dn);               \
    gc = (fiv - c_ * gc) * rd;                                 \
    ec = ((am1v) * (am1v)) * rd;                               \
    ap1 = a0; a0 = (am1v);                                     \
  }

  // Phase A: right-halo descend, groups 17..10 (no stores)
  if (!last) {
    #pragma unroll
    for (int g = 17; g >= 10; --g) {
      const float4 pA = A4[f4b + g - 2];
      const float4 pF = F4[f4b + g - 2];
      STEP(curA.z, fcur.w)
      STEP(curA.y, fcur.z)
      STEP(curA.x, fcur.y)
      STEP(lowA.w, fcur.x)
      curA = lowA; lowA = pA; fcur = flow; flow = pF;
    }
  }

  // Phase B: stored sweep, groups 9..0 (t = 4g+c, compile-time)
  #pragma unroll
  for (int g = 9; g >= 0; --g) {
    int pidx = f4b + g - 2;
    if (pidx < 0) pidx = 0;                // value unused when clamped
    const float4 pA = A4[pidx];
    const float4 pF = F4[pidx];
    float lw = lowA.w;
    if (g == 0 && first) lw = 0.0f;        // a_0 = 0
    STEP(curA.z, fcur.w)  gp[4*g+3] = gc; ep[4*g+3] = ec;
    STEP(curA.y, fcur.z)  gp[4*g+2] = gc; ep[4*g+2] = ec;
    STEP(curA.x, fcur.y)  gp[4*g+1] = gc; ep[4*g+1] = ec;
    STEP(lw,     fcur.x)  gp[4*g+0] = gc; ep[4*g+0] = ec;
    curA = lowA; lowA = pA; fcur = flow; flow = pF;
  }
#undef STEP

  // Substitution: u_i = gp - ep*u_{i-1}; write t in [tmin, tmin+32)
  const int tmin = first ? 0 : kHL;
  float up = 0.0f;
  float4 pk;
  #pragma unroll
  for (int t = 0; t < kR; ++t) {
    const float uv = fmaf(-ep[t], up, gp[t]);
    up = uv;
    const int ph = t & 3;
    if      (ph == 0) pk.x = uv;
    else if (ph == 1) pk.y = uv;
    else if (ph == 2) pk.z = uv;
    else {
      pk.w = uv;
      if (t - 3 >= tmin && t < tmin + kCH) {
        *reinterpret_cast<float4*>(&U[sL + t - 3]) = pk;
      }
    }
  }
}

extern "C" void kernel_launch(void* const* d_in, const int* in_sizes, int n_in,
                              void* d_out, int out_size, void* d_ws, size_t ws_size,
                              hipStream_t stream) {
  const float* alpha = (const float*)d_in[0];
  const float* f     = (const float*)d_in[1];
  float*       uo    = (float*)d_out;
  const dim3 grid((8192 / ROWS) * (kNC / CPB));   // 256 * 16 = 4096 blocks
  thomas_v3<<<grid, THREADS, 0, stream>>>(alpha, f, uo);
}

// Round 4
// 63.357 us; speedup vs baseline: 1.4994x; 1.2205x over previous
//
#include <hip/hip_runtime.h>

// Batched Thomas tridiagonal solve, B=8192 rows, N=4096.
//   a_i = alpha[i-1]^2 (a_0=0); b_i = max(5+alpha[i]^3, 0.01);
//   c_i = alpha[i+1]^2 + 2*alpha[i+1]; rhs f (shared across rows).
//
// Chunked UL elimination with halos (diag dominant: backward decay <=0.70/step
// -> right halo H=32 err ~1e-5; forward decay <=0.235/step -> left halo HL=8).
//
// R4: coalesced stores. R3's global stores had 64 lanes in 64 different rows
// -> 64 line-transactions per store instr, 4 partial writes per line. Now
// substitution writes to an LDS out-tile (overlaid on sA, stride 260 dw =
// volume-floor bank usage), then each wave dumps 8 full rows as contiguous
// 1KB bursts (16 lines/instr, each line written once, in full).

namespace {
constexpr int kN   = 4096;
constexpr int kCH  = 32;             // outputs per thread
constexpr int kHL  = 8;              // left halo
constexpr int kH   = 32;             // right halo
constexpr int kR   = kCH + kHL;      // stored region = 40 (10 groups of 4)
constexpr int kNC  = kN / kCH;       // 128 chunks per row
constexpr int ROWS = 32;
constexpr int CPB  = 8;              // chunks per block
constexpr int THREADS = ROWS * CPB;  // 256
constexpr int F4PR = 76;             // staged float4/row: cols [base-12, base+292)
constexpr int STRIDE_DW = 308;       // 76*4 + 4 pad; 308 % 32 == 20
constexpr int OUT_STRIDE = 260;      // out tile row stride (dw); 260 % 32 == 4
}

__global__ __launch_bounds__(THREADS) void thomas_v4(
    const float* __restrict__ alpha,
    const float* __restrict__ f,
    float* __restrict__ u)
{
  __shared__ float sMem[ROWS * STRIDE_DW];  // 39424 B; alpha panel, later out tile
  __shared__ float sF[F4PR * 4];            // 1216 B

  const int bid  = blockIdx.x;
  const int cg   = bid & 15;                // chunk group (16 per row)
  const int r0   = (bid >> 4) * ROWS;
  const int base = cg * (CPB * kCH);        // cg*256
  const int cbase4 = cg * 64 - 3;           // first staged global f4 index
  const int tid  = threadIdx.x;

  // ---- stage alpha panel (coalesced float4) ----
  #pragma unroll
  for (int it = 0; it < 10; ++it) {
    const int idx = tid + it * THREADS;
    if (idx < ROWS * F4PR) {
      const int row = idx / F4PR;
      const int c4  = idx - row * F4PR;
      int g4 = cbase4 + c4;
      g4 = (g4 < 0) ? 0 : ((g4 > kN / 4 - 1) ? kN / 4 - 1 : g4);  // clamp; dups unused
      const float4 v = *reinterpret_cast<const float4*>(
          alpha + (size_t)(r0 + row) * kN + (size_t)g4 * 4);
      *reinterpret_cast<float4*>(&sMem[row * STRIDE_DW + c4 * 4]) = v;
    }
  }
  if (tid < F4PR) {
    int g4 = cbase4 + tid;
    g4 = (g4 < 0) ? 0 : ((g4 > kN / 4 - 1) ? kN / 4 - 1 : g4);
    *reinterpret_cast<float4*>(&sF[tid * 4]) =
        *reinterpret_cast<const float4*>(f + (size_t)g4 * 4);
  }
  __syncthreads();

  // ---- per-thread chunk solve ----
  const int j = tid & 31;                   // row-local
  const int q = tid >> 5;                   // chunk-local 0..7
  const int k = cg * CPB + q;

  const bool first = (k == 0);
  const bool last  = (k == kNC - 1);
  const int  s   = k * kCH;
  const int  sL  = first ? 0 : (s - kHL);
  const int  off = 12 - base;               // LDS dword = global col + off
  const int  f4b = (sL + off) >> 2;         // LDS f4 index of group 0

  const float4* __restrict__ A4 = reinterpret_cast<const float4*>(&sMem[j * STRIDE_DW]);
  const float4* __restrict__ F4 = reinterpret_cast<const float4*>(sF);

  float gp[kR], ep[kR];
  float ec = 0.0f, gc = 0.0f, ap1 = 0.0f;   // zero carry: first step's c*carry = 0
  const int ghi = last ? 9 : 17;
  float4 curA = A4[f4b + ghi];
  float4 lowA = A4[f4b + ghi - 1];
  float4 fcur = F4[f4b + ghi];
  float4 flow = F4[f4b + ghi - 1];
  float a0 = curA.w;

#define STEP(am1v, fiv)                                        \
  {                                                            \
    const float c_  = ap1 * (ap1 + 2.0f);                      \
    const float b_  = fmaxf(fmaf(a0 * a0, a0, 5.0f), 0.01f);   \
    const float dn  = fmaf(-c_, ec, b_);                       \
    const float rd  = __builtin_amdgcn_rcpf(dn);               \
    gc = (fiv - c_ * gc) * rd;                                 \
    ec = ((am1v) * (am1v)) * rd;                               \
    ap1 = a0; a0 = (am1v);                                     \
  }

  // Phase A: right-halo descend, groups 17..10 (no stores)
  if (!last) {
    #pragma unroll
    for (int g = 17; g >= 10; --g) {
      const float4 pA = A4[f4b + g - 2];
      const float4 pF = F4[f4b + g - 2];
      STEP(curA.z, fcur.w)
      STEP(curA.y, fcur.z)
      STEP(curA.x, fcur.y)
      STEP(lowA.w, fcur.x)
      curA = lowA; lowA = pA; fcur = flow; flow = pF;
    }
  }

  // Phase B: stored sweep, groups 9..0
  #pragma unroll
  for (int g = 9; g >= 0; --g) {
    int pidx = f4b + g - 2;
    if (pidx < 0) pidx = 0;                 // value unused when clamped
    const float4 pA = A4[pidx];
    const float4 pF = F4[pidx];
    float lw = lowA.w;
    if (g == 0 && first) lw = 0.0f;         // a_0 = 0
    STEP(curA.z, fcur.w)  gp[4*g+3] = gc; ep[4*g+3] = ec;
    STEP(curA.y, fcur.z)  gp[4*g+2] = gc; ep[4*g+2] = ec;
    STEP(curA.x, fcur.y)  gp[4*g+1] = gc; ep[4*g+1] = ec;
    STEP(lw,     fcur.x)  gp[4*g+0] = gc; ep[4*g+0] = ec;
    curA = lowA; lowA = pA; fcur = flow; flow = pF;
  }
#undef STEP

  __syncthreads();   // all sMem reads done; safe to overwrite with out tile

  // Substitution: u_i = gp - ep*u_{i-1}; out cols q*32 .. q*32+31 of row j
  const int tmin = first ? 0 : kHL;
  const int obase = j * OUT_STRIDE + q * kCH - 3 - tmin;  // + t at ph==3
  float up = 0.0f;
  float4 pk;
  #pragma unroll
  for (int t = 0; t < kR; ++t) {
    const float uv = fmaf(-ep[t], up, gp[t]);
    up = uv;
    const int ph = t & 3;
    if      (ph == 0) pk.x = uv;
    else if (ph == 1) pk.y = uv;
    else if (ph == 2) pk.z = uv;
    else {
      pk.w = uv;
      if (t - 3 >= tmin && t < tmin + kCH) {
        *reinterpret_cast<float4*>(&sMem[obase + t]) = pk;
      }
    }
  }

  __syncthreads();   // out tile complete

  // Coalesced dump: each wave writes 8 full rows as contiguous 1KB bursts
  const int wave = tid >> 6;                // 0..3
  const int lane = tid & 63;
  #pragma unroll
  for (int rr = 0; rr < 8; ++rr) {
    const int row = wave * 8 + rr;
    const float4 v = *reinterpret_cast<const float4*>(
        &sMem[row * OUT_STRIDE + lane * 4]);
    *reinterpret_cast<float4*>(
        u + (size_t)(r0 + row) * kN + base + lane * 4) = v;
  }
}

extern "C" void kernel_launch(void* const* d_in, const int* in_sizes, int n_in,
                              void* d_out, int out_size, void* d_ws, size_t ws_size,
                              hipStream_t stream) {
  const float* alpha = (const float*)d_in[0];
  const float* f     = (const float*)d_in[1];
  float*       uo    = (float*)d_out;
  const dim3 grid((8192 / ROWS) * (kNC / CPB));   // 256 * 16 = 4096 blocks
  thomas_v4<<<grid, THREADS, 0, stream>>>(alpha, f, uo);
}

// Round 5
// 59.685 us; speedup vs baseline: 1.5917x; 1.0615x over previous
//
#include <hip/hip_runtime.h>

// Batched Thomas tridiagonal solve, B=8192 rows, N=4096.
//   a_i = alpha[i-1]^2 (a_0=0); b_i = max(5+alpha[i]^3, 0.01);
//   c_i = alpha[i+1]^2 + 2*alpha[i+1]; rhs f (shared across rows).
//
// Chunked UL elimination with halos (diag dominant: backward decay <=0.70/step
// -> right halo H=32 err ~1e-5; forward decay <=0.235/step -> left halo HL=8).
//
// R5: barrier-free wave-private tiles. R4's stage->barrier->compute->barrier->
// dump convoy left VALU (31%) and HBM (32%) both idle in alternation. Now each
// WAVE owns an 8-row x 256-col tile with a private LDS region: stages it,
// computes, dumps - zero __syncthreads (intra-wave lockstep + lgkmcnt gives
// ordering). Waves desync naturally -> stage/compute/dump of different waves
// overlap. 128-thread blocks, 22.1 KB LDS -> 7 blocks/CU = 14 waves/CU.
// STEP math identical to R4 (absmax must stay 0.00390625).

namespace {
constexpr int kN   = 4096;
constexpr int kCH  = 32;              // outputs per lane
constexpr int kHL  = 8;               // left halo
constexpr int kR   = kCH + kHL;       // stored region = 40
constexpr int kNC  = kN / kCH;        // 128 chunks per row
constexpr int RPW  = 8;               // rows per wave
constexpr int CPW  = 8;               // chunks per wave (256-col window)
constexpr int WAVES = 2;
constexpr int THREADS = 64 * WAVES;   // 128
constexpr int F4PR = 76;              // staged f4 per row: cols [base-12, base+292)
constexpr int ST4  = 77;              // row stride in f4 (308 dw; 308%32==20)
constexpr int WLDS4 = RPW * ST4 + F4PR;  // 692 f4 per wave (A panel + f span)
}

__global__ __launch_bounds__(THREADS) void thomas_v5(
    const float4* __restrict__ alpha4,
    const float4* __restrict__ f4,
    float4* __restrict__ u4)
{
  __shared__ float4 sM[WAVES * WLDS4];   // 22144 B

  const int bid  = blockIdx.x;
  const int cw   = bid & 15;                    // col window (256 cols)
  const int r0   = (bid >> 4) * (WAVES * RPW);  // first row of block
  const int tid  = threadIdx.x;
  const int w    = tid >> 6;
  const int lane = tid & 63;
  const int cbase4 = cw * 64 - 3;               // first staged global f4 col

  float4* __restrict__ sA = sM + w * WLDS4;             // [RPW][ST4]
  float4* __restrict__ sF = sM + w * WLDS4 + RPW * ST4; // [F4PR]

  // ---- wave-private staging (coalesced float4, reg->LDS) ----
  const int rw0 = r0 + w * RPW;
  #pragma unroll
  for (int it = 0; it < 10; ++it) {
    const int idx = lane + it * 64;
    if (idx < RPW * F4PR) {                      // 608
      const int row = idx / F4PR;
      const int c4  = idx - row * F4PR;
      int g4 = cbase4 + c4;
      g4 = (g4 < 0) ? 0 : ((g4 > kN / 4 - 1) ? kN / 4 - 1 : g4);  // dups unused
      sA[row * ST4 + c4] = alpha4[(size_t)(rw0 + row) * (kN / 4) + g4];
    }
  }
  #pragma unroll
  for (int it = 0; it < 2; ++it) {
    const int idx = lane + it * 64;
    if (idx < F4PR) {
      int g4 = cbase4 + idx;
      g4 = (g4 < 0) ? 0 : ((g4 > kN / 4 - 1) ? kN / 4 - 1 : g4);
      sF[idx] = f4[g4];
    }
  }
  // no __syncthreads: wave reads only its own region (lockstep + lgkmcnt)

  // ---- per-lane chunk solve ----
  const int j = lane >> 3;                 // row-local 0..7
  const int q = lane & 7;                  // chunk-local 0..7
  const int k = cw * CPW + q;
  const bool first = (k == 0);
  const bool last  = (k == kNC - 1);
  const int  f4b = first ? 3 : (q * 8 + 1);  // = (sL + 12 - base)/4

  const float4* __restrict__ A4 = sA + j * ST4;
  const float4* __restrict__ F4 = sF;

  float gp[kR], ep[kR];
  float ec = 0.0f, gc = 0.0f, ap1 = 0.0f;  // zero carry: first step's c*carry=0
  const int ghi = last ? 9 : 17;
  float4 curA = A4[f4b + ghi];
  float4 lowA = A4[f4b + ghi - 1];
  float4 fcur = F4[f4b + ghi];
  float4 flow = F4[f4b + ghi - 1];
  float a0 = curA.w;

#define STEP(am1v, fiv)                                        \
  {                                                            \
    const float c_  = ap1 * (ap1 + 2.0f);                      \
    const float b_  = fmaxf(fmaf(a0 * a0, a0, 5.0f), 0.01f);   \
    const float dn  = fmaf(-c_, ec, b_);                       \
    const float rd  = __builtin_amdgcn_rcpf(dn);               \
    gc = (fiv - c_ * gc) * rd;                                 \
    ec = ((am1v) * (am1v)) * rd;                               \
    ap1 = a0; a0 = (am1v);                                     \
  }

  // Phase A: right-halo descend, groups 17..10 (no stores)
  if (!last) {
    #pragma unroll
    for (int g = 17; g >= 10; --g) {
      const float4 pA = A4[f4b + g - 2];
      const float4 pF = F4[f4b + g - 2];
      STEP(curA.z, fcur.w)
      STEP(curA.y, fcur.z)
      STEP(curA.x, fcur.y)
      STEP(lowA.w, fcur.x)
      curA = lowA; lowA = pA; fcur = flow; flow = pF;
    }
  }

  // Phase B: stored sweep, groups 9..0
  #pragma unroll
  for (int g = 9; g >= 0; --g) {
    int pidx = f4b + g - 2;
    if (pidx < 0) pidx = 0;                // value unused when clamped
    const float4 pA = A4[pidx];
    const float4 pF = F4[pidx];
    float lw = lowA.w;
    if (g == 0 && first) lw = 0.0f;        // a_0 = 0
    STEP(curA.z, fcur.w)  gp[4*g+3] = gc; ep[4*g+3] = ec;
    STEP(curA.y, fcur.z)  gp[4*g+2] = gc; ep[4*g+2] = ec;
    STEP(curA.x, fcur.y)  gp[4*g+1] = gc; ep[4*g+1] = ec;
    STEP(lw,     fcur.x)  gp[4*g+0] = gc; ep[4*g+0] = ec;
    curA = lowA; lowA = pA; fcur = flow; flow = pF;
  }
#undef STEP

  // ---- substitution into wave-private out-tile (overlays sA; all LDS reads
  // of this wave are complete in program order, lockstep => no race) ----
  const int tmin = first ? 0 : kHL;
  float up = 0.0f;
  float4 pk;
  #pragma unroll
  for (int t = 0; t < kR; ++t) {
    const float uv = fmaf(-ep[t], up, gp[t]);
    up = uv;
    const int ph = t & 3;
    if      (ph == 0) pk.x = uv;
    else if (ph == 1) pk.y = uv;
    else if (ph == 2) pk.z = uv;
    else {
      pk.w = uv;
      if (t - 3 >= tmin && t < tmin + kCH) {
        sA[j * ST4 + q * 8 + ((t - 3 - tmin) >> 2)] = pk;
      }
    }
  }

  // ---- coalesced dump: one full 1KB row-segment per store instruction ----
  #pragma unroll
  for (int it = 0; it < RPW; ++it) {
    const float4 v = sA[it * ST4 + lane];
    u4[(size_t)(rw0 + it) * (kN / 4) + cw * 64 + lane] = v;
  }
}

extern "C" void kernel_launch(void* const* d_in, const int* in_sizes, int n_in,
                              void* d_out, int out_size, void* d_ws, size_t ws_size,
                              hipStream_t stream) {
  const float4* alpha = (const float4*)d_in[0];
  const float4* f     = (const float4*)d_in[1];
  float4*       uo    = (float4*)d_out;
  // grid: 512 row-groups (16 rows) x 16 col-windows (256 cols) = 8192 blocks
  thomas_v5<<<dim3(8192), THREADS, 0, stream>>>(alpha, f, uo);
}